// Round 7
// baseline (69.350 us; speedup 1.0000x reference)
//
#include <hip/hip_runtime.h>

#define GAMMA   0.99f
#define EPSILON 1e-8f
#define CLIPR   10.0f
#define VAR_MOM 0.99f

constexpr int T = 4096;
constexpr int B = 4096;
constexpr int GSEG = 16;

// ---------------------------------------------------------------------------
// K1 (max-occupancy mapping): VPT=1 scalar columns. grid = (B/256, C) blocks
// = 16*C; at C=128 -> 2048 blocks = 8 blocks/CU = 32 waves/CU (hw max).
// Session evidence (R1-R6): per-wave software pipelining (18-deep asm, R5)
// and DRAM burst shaping (R6) both null; BW tracks resident waves only
// (~5 cache lines in flight per wave). So: minimum VGPR, maximum waves.
// ---------------------------------------------------------------------------
template <int L>
__global__ __launch_bounds__(256, 8) void chunk_scan_v1(
    const float* __restrict__ rewards,
    const float* __restrict__ dones,
    float* __restrict__ arrs,   // 7 arrays, stride S=C*B
    int C) {
    const int b  = blockIdx.x * blockDim.x + threadIdx.x;  // column [0,B)
    const int c  = blockIdx.y;
    const int t0 = c * L;

    float v = 0.f, p = 1.f, sv = 0.f, sp = 0.f, sv2 = 0.f, svp = 0.f, sp2 = 0.f;

#pragma unroll 4
    for (int j = 0; j < L; ++j) {
        const int t = t0 + L - 1 - j;
        const float r = rewards[(size_t)t * B + b];
        const float d = dones  [(size_t)t * B + b];
        const float a = GAMMA - GAMMA * d;   // gamma * (1 - d)
        v = fmaf(a, v, r);                   // local scan (carry = 0)
        p = p * a;                           // suffix decay product
        sv  += v;
        sp  += p;
        sv2  = fmaf(v, v, sv2);
        svp  = fmaf(v, p, svp);
        sp2  = fmaf(p, p, sp2);
    }

    const size_t S   = (size_t)C * B;
    const size_t idx = (size_t)c * B + b;
    arrs[0 * S + idx] = v;    // v_first
    arrs[1 * S + idx] = p;    // p_tot
    arrs[2 * S + idx] = sv;
    arrs[3 * S + idx] = sp;
    arrs[4 * S + idx] = sv2;
    arrs[5 * S + idx] = svp;
    arrs[6 * S + idx] = sp2;
}

// K2a: compose chunk summaries within each of GSEG segments per column.
__global__ void seg_compose(const float* __restrict__ arrs, int C,
                            float* __restrict__ seg) {
    const int tid = blockIdx.x * blockDim.x + threadIdx.x;
    const int b = tid & (B - 1);
    const int s = tid >> 12;
    const int Cs = C / GSEG;
    const size_t S = (size_t)C * B;
    float V = 0.f, P = 1.f, SV = 0.f, SP = 0.f, SV2 = 0.f, SVP = 0.f, SP2 = 0.f;
    for (int c = (s + 1) * Cs - 1; c >= s * Cs; --c) {
        const size_t idx = (size_t)c * B + b;
        const float vf  = arrs[0 * S + idx];
        const float pt  = arrs[1 * S + idx];
        const float sv  = arrs[2 * S + idx];
        const float sp  = arrs[3 * S + idx];
        const float sv2 = arrs[4 * S + idx];
        const float svp = arrs[5 * S + idx];
        const float sp2 = arrs[6 * S + idx];
        SV2 += sv2 + 2.f * svp * V + sp2 * V * V;
        SVP += svp * P + sp2 * V * P;
        SP2 += sp2 * P * P;
        SV  += sv + sp * V;
        SP  += sp * P;
        V = fmaf(pt, V, vf);
        P *= pt;
    }
    const size_t SG = (size_t)GSEG * B;
    const size_t o  = (size_t)s * B + b;
    seg[0 * SG + o] = V;   seg[1 * SG + o] = P;
    seg[2 * SG + o] = SV;  seg[3 * SG + o] = SP;
    seg[4 * SG + o] = SV2; seg[5 * SG + o] = SVP; seg[6 * SG + o] = SP2;
}

// K2b: finish carry across GSEG segments per column; exact sums in double.
__global__ void carry_final(const float* __restrict__ seg,
                            const float* __restrict__ return_init,
                            double* __restrict__ acc) {
    const int b = blockIdx.x * blockDim.x + threadIdx.x;
    const size_t SG = (size_t)GSEG * B;
    double s = 0.0, s2 = 0.0;
    float carry = return_init[0];
    for (int g = GSEG - 1; g >= 0; --g) {
        const size_t o = (size_t)g * B + b;
        const float V   = seg[0 * SG + o];
        const float P   = seg[1 * SG + o];
        const float SV  = seg[2 * SG + o];
        const float SP  = seg[3 * SG + o];
        const float SV2 = seg[4 * SG + o];
        const float SVP = seg[5 * SG + o];
        const float SP2 = seg[6 * SG + o];
        const double cd = (double)carry;
        s  += (double)SV  + cd * (double)SP;
        s2 += (double)SV2 + 2.0 * cd * (double)SVP + cd * cd * (double)SP2;
        carry = fmaf(P, carry, V);
    }
    __shared__ double sh_s[256];
    __shared__ double sh_s2[256];
    const int tid = threadIdx.x;
    sh_s[tid] = s; sh_s2[tid] = s2;
    __syncthreads();
    for (int stride = 128; stride > 0; stride >>= 1) {
        if (tid < stride) {
            sh_s[tid]  += sh_s[tid + stride];
            sh_s2[tid] += sh_s2[tid + stride];
        }
        __syncthreads();
    }
    if (tid == 0) {
        atomicAdd(&acc[0], sh_s[0]);
        atomicAdd(&acc[1], sh_s2[0]);
    }
}

// K2 fallback (single-level) if ws too small for seg scratch.
__global__ void carry_reduce(const float* __restrict__ arrs, int C,
                             const float* __restrict__ return_init,
                             double* __restrict__ acc) {
    const int b = blockIdx.x * blockDim.x + threadIdx.x;
    const size_t S = (size_t)C * B;
    double s = 0.0, s2 = 0.0;
    float carry = return_init[0];
#pragma unroll 4
    for (int c = C - 1; c >= 0; --c) {
        const size_t idx = (size_t)c * B + b;
        const float vf  = arrs[0 * S + idx];
        const float pt  = arrs[1 * S + idx];
        const float sv  = arrs[2 * S + idx];
        const float sp  = arrs[3 * S + idx];
        const float sv2 = arrs[4 * S + idx];
        const float svp = arrs[5 * S + idx];
        const float sp2 = arrs[6 * S + idx];
        const double cd = (double)carry;
        s  += (double)sv  + cd * (double)sp;
        s2 += (double)sv2 + 2.0 * cd * (double)svp + cd * cd * (double)sp2;
        carry = fmaf(pt, carry, vf);
    }
    __shared__ double sh_s[256];
    __shared__ double sh_s2[256];
    const int tid = threadIdx.x;
    sh_s[tid] = s; sh_s2[tid] = s2;
    __syncthreads();
    for (int stride = 128; stride > 0; stride >>= 1) {
        if (tid < stride) {
            sh_s[tid]  += sh_s[tid + stride];
            sh_s2[tid] += sh_s2[tid + stride];
        }
        __syncthreads();
    }
    if (tid == 0) {
        atomicAdd(&acc[0], sh_s[0]);
        atomicAdd(&acc[1], sh_s2[0]);
    }
}

// K3: scale = 1/sqrt(var_new + eps); out = clip(rewards * scale).
__global__ void normalize(const float* __restrict__ rewards,
                          float* __restrict__ out,
                          const double* __restrict__ acc,
                          const float* __restrict__ var_init,
                          int n4) {
    const double s  = acc[0];
    const double s2 = acc[1];
    const double n  = (double)T * (double)B;
    const double ret_var = (s2 - s * s / n) / (n - 1.0);
    const float var_new = (float)((double)var_init[0] * (double)VAR_MOM +
                                  ret_var * (1.0 - (double)VAR_MOM));
    const float scale = 1.0f / sqrtf(var_new + EPSILON);

    const float4* __restrict__ r4 = (const float4*)rewards;
    float4* __restrict__ o4 = (float4*)out;
    const int stride = gridDim.x * blockDim.x;
    for (int i = blockIdx.x * blockDim.x + threadIdx.x; i < n4; i += stride) {
        float4 x = r4[i];
        float4 y;
        y.x = fminf(fmaxf(x.x * scale, -CLIPR), CLIPR);
        y.y = fminf(fmaxf(x.y * scale, -CLIPR), CLIPR);
        y.z = fminf(fmaxf(x.z * scale, -CLIPR), CLIPR);
        y.w = fminf(fmaxf(x.w * scale, -CLIPR), CLIPR);
        o4[i] = y;
    }
}

extern "C" void kernel_launch(void* const* d_in, const int* in_sizes, int n_in,
                              void* d_out, int out_size, void* d_ws, size_t ws_size,
                              hipStream_t stream) {
    const float* rewards     = (const float*)d_in[0];
    const float* dones       = (const float*)d_in[1];
    const float* return_init = (const float*)d_in[2];
    const float* var_init    = (const float*)d_in[3];
    float* out = (float*)d_out;

    double* acc  = (double*)d_ws;
    float*  arrs = (float*)((char*)d_ws + 64);

    hipMemsetAsync(d_ws, 0, 16, stream);

    const size_t arrs256 = (size_t)7 * 256 * B * 4;
    const size_t arrs128 = (size_t)7 * 128 * B * 4;
    const size_t arrs64  = (size_t)7 * 64  * B * 4;
    const size_t segsz   = (size_t)7 * GSEG * B * 4;

    int C;
    float* segp = nullptr;
    if (ws_size >= 64 + arrs256 + segsz) {
        C = 256;   // L=16 -> 4096 blocks, 100% occupancy (2 dispatch rounds)
        segp = (float*)((char*)d_ws + 64 + arrs256);
        dim3 g1(B / 256, C);
        chunk_scan_v1<16><<<g1, 256, 0, stream>>>(rewards, dones, arrs, C);
    } else if (ws_size >= 64 + arrs128) {
        C = 128;   // L=32 -> 2048 blocks = 8/CU = 32 waves/CU (hw max)
        if (ws_size >= 64 + arrs128 + segsz) segp = (float*)((char*)d_ws + 64 + arrs128);
        dim3 g1(B / 256, C);
        chunk_scan_v1<32><<<g1, 256, 0, stream>>>(rewards, dones, arrs, C);
    } else {
        C = 64;    // L=64 -> 1024 blocks
        if (ws_size >= 64 + arrs64 + segsz) segp = (float*)((char*)d_ws + 64 + arrs64);
        dim3 g1(B / 256, C);
        chunk_scan_v1<64><<<g1, 256, 0, stream>>>(rewards, dones, arrs, C);
    }

    if (segp) {
        seg_compose<<<(B * GSEG) / 256, 256, 0, stream>>>(arrs, C, segp);
        carry_final<<<B / 256, 256, 0, stream>>>(segp, return_init, acc);
    } else {
        carry_reduce<<<B / 256, 256, 0, stream>>>(arrs, C, return_init, acc);
    }

    const int n4 = (T * B) / 4;
    normalize<<<4096, 256, 0, stream>>>(rewards, out, acc, var_init, n4);
}